// Round 7
// baseline (291.953 us; speedup 1.0000x reference)
//
#include <hip/hip_runtime.h>
#include <math.h>

#define T_ 32
#define B_ 16
#define V_ 30000
#define V4 7500
#define D_ 300
#define DQKV_ 150
#define KSTR 152              // KC row stride (pad 150 -> 152 floats, 16B aligned)
#define K_ 10
#define G_ 32
#define N_ 320                // K*G
#define S_ 25000
#define S4 6250
#define NTS 1024              // scan kernel threads
#define NWS 16
#define NTA 512               // attn kernel threads
#define GR 48                 // gemm rows per block
#define NBK 521               // ceil(25000/48)
#define NBQ 11                // ceil(512/48)

__device__ __forceinline__ bool better(float av, int ai, float bv, int bi) {
    // ranks (av,ai) strictly before (bv,bi): higher value, ties -> lower index
    return (av > bv) || (av == bv && ai < bi);
}

// ================= Kernel 1: KC = SC@Wk, Q = lc@Wq (row-padded to KSTR) ======
__global__ __launch_bounds__(256) void gemm_kernel(
    const float* __restrict__ SC, const float* __restrict__ lc,
    const float* __restrict__ Wk, const float* __restrict__ Wq,
    float* __restrict__ KC, float* __restrict__ Qws)
{
    __shared__ __align__(16) float at[GR * D_];    // 57.6 KB
    const int bid = blockIdx.x;
    const float* A; const float* Bw; float* O; int row0, M;
    if (bid < NBK) { A = SC; Bw = Wk; O = KC;  row0 = bid * GR;         M = S_; }
    else           { A = lc; Bw = Wq; O = Qws; row0 = (bid - NBK) * GR; M = T_ * B_; }
    const int nr = (M - row0 < GR) ? (M - row0) : GR;

    const float4* a4 = (const float4*)(A + (size_t)row0 * D_);
    float4* t4 = (float4*)at;
    for (int i = threadIdx.x; i < nr * (D_ / 4); i += 256) t4[i] = a4[i];
    __syncthreads();

    const int jj = threadIdx.x & 31;       // 32 col-lanes (coalesced Wk reads)
    const int rr = threadIdx.x >> 5;       // 8 row-groups
    float acc[6][5];
    #pragma unroll
    for (int t = 0; t < 6; ++t)
        #pragma unroll
        for (int c = 0; c < 5; ++c) acc[t][c] = 0.f;

    #pragma unroll 2
    for (int d = 0; d < D_; ++d) {
        float w[5];
        #pragma unroll
        for (int c = 0; c < 5; ++c) {
            int j = jj + 32 * c; if (j >= DQKV_) j = 0;   // clamp, never stored
            w[c] = Bw[d * DQKV_ + j];
        }
        #pragma unroll
        for (int t = 0; t < 6; ++t) {
            float av = at[(rr + 8 * t) * D_ + d];   // r<48 always in-bounds LDS
            #pragma unroll
            for (int c = 0; c < 5; ++c) acc[t][c] += av * w[c];
        }
    }
    #pragma unroll
    for (int t = 0; t < 6; ++t) {
        int r = rr + 8 * t;
        if (r < nr) {
            #pragma unroll
            for (int c = 0; c < 5; ++c) {
                int j = jj + 32 * c;
                if (j < DQKV_) O[(size_t)(row0 + r) * KSTR + j] = acc[t][c];
            }
        }
    }
    // zero the 2-float row pad (attn reads rows as 38 float4)
    for (int i = threadIdx.x; i < nr * 2; i += 256)
        O[(size_t)(row0 + (i >> 1)) * KSTR + DQKV_ + (i & 1)] = 0.f;
}

// ================= Kernel 2: fill + per-row exact top-10 =====================
__global__ __launch_bounds__(NTS, 4) void scan_kernel(
    const float* __restrict__ pred, float* __restrict__ out,
    int* __restrict__ wstop)
{
    const int row = blockIdx.x, tid = threadIdx.x;
    const int lane = tid & 63, wave = tid >> 6;
    __shared__ float wcv[NWS * K_];
    __shared__ int   wci[NWS * K_];

    // fill output row with log(1e-8); stores drain by BAR1
    const float FILL = -18.420680743952367f;
    {
        float4 f4 = make_float4(FILL, FILL, FILL, FILL);
        float4* o4 = (float4*)(out + (size_t)row * S_);
        #pragma unroll
        for (int k = 0; k < 7; ++k) { int i = tid + k * NTS; if (i < S4) o4[i] = f4; }
    }

    // 8 float4 staged up-front (MLP 8), exact per-thread top-10
    float tv[K_]; int ti[K_];
    #pragma unroll
    for (int s = 0; s < K_; ++s) { tv[s] = -INFINITY; ti[s] = 0x7fffffff; }
    {
        const float4* p4 = (const float4*)(pred + (size_t)row * V_);
        const float4 NEG = make_float4(-INFINITY, -INFINITY, -INFINITY, -INFINITY);
        float4 a[8]; int ib[8];
        #pragma unroll
        for (int u = 0; u < 8; ++u) {
            int i = tid + u * NTS;
            a[u]  = (i < V4) ? p4[i] : NEG;
            ib[u] = (i < V4) ? i * 4 : 0x7ffffff0;
        }
        #pragma unroll
        for (int u = 0; u < 8; ++u) {
            float x = a[u].x, y = a[u].y, z = a[u].z, w = a[u].w;
            float m4 = fmaxf(fmaxf(x, y), fmaxf(z, w));
            if (!(m4 < tv[K_-1])) {      // quad skip vs own 10th: exact
                float vals[4] = {x, y, z, w};
                #pragma unroll
                for (int c = 0; c < 4; ++c) {
                    float val = vals[c];
                    int   idx = ib[u] + c;
                    if (better(val, idx, tv[K_-1], ti[K_-1])) {
                        tv[K_-1] = val; ti[K_-1] = idx;
                        #pragma unroll
                        for (int s = K_-1; s > 0; --s) {
                            if (better(tv[s], ti[s], tv[s-1], ti[s-1])) {
                                float fx = tv[s]; tv[s] = tv[s-1]; tv[s-1] = fx;
                                int   iy = ti[s]; ti[s] = ti[s-1]; ti[s-1] = iy;
                            }
                        }
                    }
                }
            }
        }
    }

    // per-wave top-10 via 10 shfl-argmax passes
    for (int p = 0; p < K_; ++p) {
        float bv = tv[0]; int bi = ti[0];
        #pragma unroll
        for (int s = 1; s < K_; ++s)
            if (better(tv[s], ti[s], bv, bi)) { bv = tv[s]; bi = ti[s]; }
        #pragma unroll
        for (int off = 32; off; off >>= 1) {
            float ov = __shfl_xor(bv, off, 64);
            int   oi = __shfl_xor(bi, off, 64);
            if (better(ov, oi, bv, bi)) { bv = ov; bi = oi; }
        }
        if (lane == 0) { wcv[wave * K_ + p] = bv; wci[wave * K_ + p] = bi; }
        #pragma unroll
        for (int s = 0; s < K_; ++s)
            if (ti[s] == bi) tv[s] = -INFINITY;
    }
    __syncthreads();

    // wave 0 merges 160 candidates -> global top-10 -> ws
    if (wave == 0) {
        float c0v = wcv[lane],      c1v = wcv[64 + lane];
        int   c0i = wci[lane],      c1i = wci[64 + lane];
        float c2v = (lane < 32) ? wcv[128 + lane] : -INFINITY;
        int   c2i = (lane < 32) ? wci[128 + lane] : 0x7fffffff;
        for (int p = 0; p < K_; ++p) {
            float bv = c0v; int bi = c0i;
            if (better(c1v, c1i, bv, bi)) { bv = c1v; bi = c1i; }
            if (better(c2v, c2i, bv, bi)) { bv = c2v; bi = c2i; }
            #pragma unroll
            for (int off = 32; off; off >>= 1) {
                float ov = __shfl_xor(bv, off, 64);
                int   oi = __shfl_xor(bi, off, 64);
                if (better(ov, oi, bv, bi)) { bv = ov; bi = oi; }
            }
            if (lane == 0) wstop[row * K_ + p] = bi;
            if (c0i == bi) c0v = -INFINITY;
            if (c1i == bi) c1v = -INFINITY;
            if (c2i == bi) c2v = -INFINITY;
        }
    }
}

// ================= Kernel 3: neighbours + logits + softmax + scatter =========
__global__ __launch_bounds__(NTA) void attn_kernel(
    const float* __restrict__ KC, const float* __restrict__ Qws,
    const int* __restrict__ nbt, const int* __restrict__ wstop,
    float* __restrict__ out)
{
    const int row = blockIdx.x, tid = threadIdx.x;
    const int lane = tid & 63, wave = tid >> 6;
    __shared__ int   topg[K_];
    __shared__ __align__(16) float qsh[KSTR];
    __shared__ int   nidx[N_];
    __shared__ float lg[N_];
    __shared__ int   kills[N_];
    __shared__ float redA[8], redB[8];
    float* outrow = out + (size_t)row * S_;

    if (tid < KSTR) qsh[tid] = Qws[(size_t)row * KSTR + tid];
    else if (tid >= 160 && tid < 160 + K_) topg[tid - 160] = wstop[row * K_ + (tid - 160)];
    else if (tid >= 192) kills[tid - 192] = 0;        // 320 flags
    __syncthreads();                                   // BAR1

    if (tid < N_) nidx[tid] = nbt[topg[tid >> 5] * G_ + (tid & 31)];
    __syncthreads();                                   // BAR2

    // logits[n] = q . KC[nidx[n]] * ISC : 2 lanes per dot, 19 float4 each
    const float ISC = 0.08164965809277260327f;   // 1/sqrt(150)
    const float4* q4 = (const float4*)qsh;
    float v = -INFINITY;
    for (int s = tid; s < 2 * N_; s += NTA) {
        int n = s >> 1, h = s & 1;
        const float4* kc4 = (const float4*)(KC + (size_t)nidx[n] * KSTR);
        float acc = 0.f;
        #pragma unroll
        for (int cc = 0; cc < 19; ++cc) {
            float4 x = kc4[h * 19 + cc];
            float4 b = q4[h * 19 + cc];
            acc += x.x * b.x + x.y * b.y + x.z * b.z + x.w * b.w;
        }
        acc += __shfl_xor(acc, 1, 64);
        if (h == 0) lg[n] = acc * ISC;
    }
    __syncthreads();                                   // BAR3

    // softmax stats over 320
    v = (tid < N_) ? lg[tid] : -INFINITY;
    float m = v;
    #pragma unroll
    for (int off = 32; off; off >>= 1) m = fmaxf(m, __shfl_xor(m, off, 64));
    if (lane == 0) redA[wave] = m;
    __syncthreads();                                   // BAR4
    m = redA[0];
    #pragma unroll
    for (int w = 1; w < 8; ++w) m = fmaxf(m, redA[w]);

    float ss = (tid < N_) ? expf(v - m) : 0.f;
    #pragma unroll
    for (int off = 32; off; off >>= 1) ss += __shfl_xor(ss, off, 64);
    if (lane == 0) redB[wave] = ss;
    __syncthreads();                                   // BAR5
    float tot = redB[0];
    #pragma unroll
    for (int w = 1; w < 8; ++w) tot += redB[w];
    float lsum = logf(tot);

    // last-write-wins duplicate detection: 1280 chunk-scans of width 80
    for (int s = tid; s < 4 * N_; s += NTA) {
        int n = s >> 2, c = s & 3;
        int sidx = nidx[n];
        int clo = c * 80;
        int lo = (n + 1 > clo) ? n + 1 : clo;
        int hi = clo + 80;
        bool mt = false;
        #pragma unroll 4
        for (int n2 = lo; n2 < hi; ++n2) mt |= (nidx[n2] == sidx);
        if (mt) kills[n] = 1;
    }
    __syncthreads();                                   // BAR6

    if (tid < N_ && !kills[tid]) outrow[nidx[tid]] = (v - m) - lsum;
}

// ================= Fallback: R6 fused single kernel (needs no ws) ============
__global__ __launch_bounds__(NTS, 4) void selfatt_fused(
    const float* __restrict__ pred, const float* __restrict__ lc,
    const float* __restrict__ SC, const float* __restrict__ Wq,
    const float* __restrict__ Wk, const int* __restrict__ nbt,
    float* __restrict__ out)
{
    const int row = blockIdx.x, tid = threadIdx.x;
    const int lane = tid & 63, wave = tid >> 6;
    __shared__ float wcv[NWS * K_];
    __shared__ int   wci[NWS * K_];
    __shared__ int   topg[K_];
    __shared__ float lcs[D_];
    __shared__ float qs[DQKV_];
    __shared__ __align__(16) float qks[D_];
    __shared__ int   nidx[N_];
    __shared__ float lg[N_];
    __shared__ int   kills[N_];
    __shared__ float redA[NWS], redB[NWS];
    float* outrow = out + (size_t)row * S_;
    const float FILL = -18.420680743952367f;
    {
        float4 f4 = make_float4(FILL, FILL, FILL, FILL);
        float4* o4 = (float4*)outrow;
        #pragma unroll
        for (int k = 0; k < 7; ++k) { int i = tid + k * NTS; if (i < S4) o4[i] = f4; }
    }
    float tv[K_]; int ti[K_];
    #pragma unroll
    for (int s = 0; s < K_; ++s) { tv[s] = -INFINITY; ti[s] = 0x7fffffff; }
    {
        const float4* p4 = (const float4*)(pred + (size_t)row * V_);
        const float4 NEG = make_float4(-INFINITY, -INFINITY, -INFINITY, -INFINITY);
        float4 a[8]; int ib[8];
        #pragma unroll
        for (int u = 0; u < 8; ++u) {
            int i = tid + u * NTS;
            a[u]  = (i < V4) ? p4[i] : NEG;
            ib[u] = (i < V4) ? i * 4 : 0x7ffffff0;
        }
        #pragma unroll
        for (int u = 0; u < 8; ++u) {
            float x = a[u].x, y = a[u].y, z = a[u].z, w = a[u].w;
            float m4 = fmaxf(fmaxf(x, y), fmaxf(z, w));
            if (!(m4 < tv[K_-1])) {
                float vals[4] = {x, y, z, w};
                #pragma unroll
                for (int c = 0; c < 4; ++c) {
                    float val = vals[c];
                    int   idx = ib[u] + c;
                    if (better(val, idx, tv[K_-1], ti[K_-1])) {
                        tv[K_-1] = val; ti[K_-1] = idx;
                        #pragma unroll
                        for (int s = K_-1; s > 0; --s) {
                            if (better(tv[s], ti[s], tv[s-1], ti[s-1])) {
                                float fx = tv[s]; tv[s] = tv[s-1]; tv[s-1] = fx;
                                int   iy = ti[s]; ti[s] = ti[s-1]; ti[s-1] = iy;
                            }
                        }
                    }
                }
            }
        }
    }
    for (int p = 0; p < K_; ++p) {
        float bv = tv[0]; int bi = ti[0];
        #pragma unroll
        for (int s = 1; s < K_; ++s)
            if (better(tv[s], ti[s], bv, bi)) { bv = tv[s]; bi = ti[s]; }
        #pragma unroll
        for (int off = 32; off; off >>= 1) {
            float ov = __shfl_xor(bv, off, 64);
            int   oi = __shfl_xor(bi, off, 64);
            if (better(ov, oi, bv, bi)) { bv = ov; bi = oi; }
        }
        if (lane == 0) { wcv[wave * K_ + p] = bv; wci[wave * K_ + p] = bi; }
        #pragma unroll
        for (int s = 0; s < K_; ++s)
            if (ti[s] == bi) tv[s] = -INFINITY;
    }
    __syncthreads();
    if (wave == 0) {
        float c0v = wcv[lane],      c1v = wcv[64 + lane];
        int   c0i = wci[lane],      c1i = wci[64 + lane];
        float c2v = (lane < 32) ? wcv[128 + lane] : -INFINITY;
        int   c2i = (lane < 32) ? wci[128 + lane] : 0x7fffffff;
        for (int p = 0; p < K_; ++p) {
            float bv = c0v; int bi = c0i;
            if (better(c1v, c1i, bv, bi)) { bv = c1v; bi = c1i; }
            if (better(c2v, c2i, bv, bi)) { bv = c2v; bi = c2i; }
            #pragma unroll
            for (int off = 32; off; off >>= 1) {
                float ov = __shfl_xor(bv, off, 64);
                int   oi = __shfl_xor(bi, off, 64);
                if (better(ov, oi, bv, bi)) { bv = ov; bi = oi; }
            }
            if (lane == 0) topg[p] = bi;
            if (c0i == bi) c0v = -INFINITY;
            if (c1i == bi) c1v = -INFINITY;
            if (c2i == bi) c2v = -INFINITY;
        }
    }
    __syncthreads();
    if (tid < N_) { int g = topg[tid >> 5]; nidx[tid] = nbt[g * G_ + (tid & 31)]; }
    else if (tid < 2 * N_) kills[tid - N_] = 0;
    else if (tid >= 640 && tid < 640 + D_) lcs[tid - 640] = lc[(size_t)row * D_ + (tid - 640)];
    __syncthreads();
    if (tid < 600) {
        int j = tid >> 2, h = tid & 3;
        int d0 = h * 75;
        const float* wp = Wq + (size_t)d0 * DQKV_ + j;
        float acc = 0.f;
        #pragma unroll 5
        for (int dd = 0; dd < 75; ++dd) acc += lcs[d0 + dd] * wp[(size_t)dd * DQKV_];
        acc += __shfl_xor(acc, 1, 64);
        acc += __shfl_xor(acc, 2, 64);
        if (h == 0) qs[j] = acc;
    } else {
        int t0 = tid - 600;
        for (int s = t0; s < 4 * N_; s += 424) {
            int n = s >> 2, c = s & 3;
            int sidx = nidx[n];
            int clo = c * 80;
            int lo = (n + 1 > clo) ? n + 1 : clo;
            int hi = clo + 80;
            bool mt = false;
            #pragma unroll 4
            for (int n2 = lo; n2 < hi; ++n2) mt |= (nidx[n2] == sidx);
            if (mt) kills[n] = 1;
        }
    }
    __syncthreads();
    if (tid < 600) {
        int d = tid >> 1, h = tid & 1;
        int j0 = h * 75;
        const float* wrow = Wk + (size_t)d * DQKV_ + j0;
        float acc = 0.f;
        #pragma unroll 5
        for (int jj = 0; jj < 75; ++jj) acc += wrow[jj] * qs[j0 + jj];
        acc += __shfl_xor(acc, 1, 64);
        if (h == 0) qks[d] = acc;
    }
    __syncthreads();
    const float ISC = 0.08164965809277260327f;
    const float4* q4 = (const float4*)qks;
    for (int s = tid; s < 8 * N_; s += NTS) {
        int n = s >> 3, h = s & 7;
        const float4* sc4 = (const float4*)(SC + (size_t)nidx[n] * D_);
        int c0 = h * 9;
        float acc = 0.f;
        #pragma unroll
        for (int cc = 0; cc < 9; ++cc) {
            float4 a = sc4[c0 + cc];
            float4 b = q4[c0 + cc];
            acc += a.x * b.x + a.y * b.y + a.z * b.z + a.w * b.w;
        }
        if (h < 3) {
            float4 a = sc4[72 + h];
            float4 b = q4[72 + h];
            acc += a.x * b.x + a.y * b.y + a.z * b.z + a.w * b.w;
        }
        acc += __shfl_xor(acc, 1, 64);
        acc += __shfl_xor(acc, 2, 64);
        acc += __shfl_xor(acc, 4, 64);
        if (h == 0) lg[n] = acc * ISC;
    }
    __syncthreads();
    float v = (tid < N_) ? lg[tid] : -INFINITY;
    float m = v;
    #pragma unroll
    for (int off = 32; off; off >>= 1) m = fmaxf(m, __shfl_xor(m, off, 64));
    if (lane == 0) redA[wave] = m;
    __syncthreads();
    m = redA[0];
    #pragma unroll
    for (int w = 1; w < NWS; ++w) m = fmaxf(m, redA[w]);
    float e = (tid < N_) ? expf(v - m) : 0.f;
    float ss = e;
    #pragma unroll
    for (int off = 32; off; off >>= 1) ss += __shfl_xor(ss, off, 64);
    if (lane == 0) redB[wave] = ss;
    __syncthreads();
    float tot = redB[0];
    #pragma unroll
    for (int w = 1; w < NWS; ++w) tot += redB[w];
    float lsum = logf(tot);
    if (tid < N_ && !kills[tid]) outrow[nidx[tid]] = (v - m) - lsum;
}

extern "C" void kernel_launch(void* const* d_in, const int* in_sizes, int n_in,
                              void* d_out, int out_size, void* d_ws, size_t ws_size,
                              hipStream_t stream) {
    const float* pred = (const float*)d_in[0];
    const float* lc   = (const float*)d_in[1];
    const float* SC   = (const float*)d_in[2];
    const float* Wq   = (const float*)d_in[3];
    const float* Wk   = (const float*)d_in[4];
    const int*   nbt  = (const int*)d_in[5];
    float* out = (float*)d_out;

    const size_t need = ((size_t)S_ * KSTR + (size_t)T_ * B_ * KSTR) * sizeof(float)
                      + (size_t)T_ * B_ * K_ * sizeof(int);
    if (ws_size >= need) {
        float* KC    = (float*)d_ws;
        float* Qws   = KC + (size_t)S_ * KSTR;
        int*   wstop = (int*)(Qws + (size_t)T_ * B_ * KSTR);
        gemm_kernel<<<dim3(NBK + NBQ), dim3(256), 0, stream>>>(SC, lc, Wk, Wq, KC, Qws);
        scan_kernel<<<dim3(T_ * B_), dim3(NTS), 0, stream>>>(pred, out, wstop);
        attn_kernel<<<dim3(T_ * B_), dim3(NTA), 0, stream>>>(KC, Qws, nbt, wstop, out);
    } else {
        selfatt_fused<<<dim3(T_ * B_), dim3(NTS), 0, stream>>>(
            pred, lc, SC, Wq, Wk, nbt, out);
    }
}

// Round 8
// 256.399 us; speedup vs baseline: 1.1387x; 1.1387x over previous
//
#include <hip/hip_runtime.h>
#include <math.h>

#define T_ 32
#define B_ 16
#define V_ 30000
#define V4 7500
#define D_ 300
#define DQKV_ 150
#define KSTR 152              // KC row stride (pad 150 -> 152 floats, 16B aligned)
#define K_ 10
#define G_ 32
#define N_ 320                // K*G
#define S_ 25000
#define S4 6250
#define GROWS 32              // gemm rows per block
#define NBK 782               // ceil(25000/32)
#define NBQ 16                // 512/32
#define NGEMM (NBK + NBQ)     // 798
#define NSCAN 1024            // 512 rows x 2 halves
#define H4 3750               // float4 per half row of pred
#define F4H 3125              // float4 per half row of out
#define NTA 512
#define NTS 1024              // fallback fused kernel
#define NWS 16

__device__ __forceinline__ bool better(float av, int ai, float bv, int bi) {
    // ranks (av,ai) strictly before (bv,bi): higher value, ties -> lower index
    return (av > bv) || (av == bv && ai < bi);
}

// ============ Kernel 1: [gemm: KC=SC@Wk, Q=lc@Wq] overlapped with [fill+scan] ==
__global__ __launch_bounds__(256, 4) void fused_stage1(
    const float* __restrict__ pred, const float* __restrict__ lc,
    const float* __restrict__ SC,   const float* __restrict__ Wq,
    const float* __restrict__ Wk,
    float* __restrict__ out, float* __restrict__ KC, float* __restrict__ Qws,
    float* __restrict__ wsv, int* __restrict__ wsi)
{
    const int b   = blockIdx.x;
    const int tid = threadIdx.x;
    __shared__ __align__(16) float at[GROWS * D_];   // 38.4 KB (gemm A-tile)
    __shared__ float wcv[4 * K_];
    __shared__ int   wci[4 * K_];

    if (b < NGEMM) {
        // ---------------- GEMM path: O[r,:150] = A[r,:] @ Bw ----------------
        const float* A; const float* Bw; float* O; int row0, M;
        if (b < NBK) { A = SC; Bw = Wk; O = KC;  row0 = b * GROWS;         M = S_; }
        else         { A = lc; Bw = Wq; O = Qws; row0 = (b - NBK) * GROWS; M = T_ * B_; }
        const int nr = (M - row0 < GROWS) ? (M - row0) : GROWS;

        const float4* a4 = (const float4*)(A + (size_t)row0 * D_);
        float4* t4 = (float4*)at;
        for (int i = tid; i < nr * (D_ / 4); i += 256) t4[i] = a4[i];
        __syncthreads();

        const int cl = tid & 31;          // col lane
        const int rg = tid >> 5;          // row group (8)
        int jc[5]; const float* wp[5];
        #pragma unroll
        for (int cc = 0; cc < 5; ++cc) {
            int j = cl + 32 * cc;
            jc[cc] = j;
            wp[cc] = Bw + (j < DQKV_ ? j : 0);   // clamp: loaded, never stored
        }
        float acc[4][5];
        #pragma unroll
        for (int t = 0; t < 4; ++t)
            #pragma unroll
            for (int cc = 0; cc < 5; ++cc) acc[t][cc] = 0.f;

        const float* arow = at + rg * 4 * D_;
        for (int d = 0; d < D_; d += 4) {            // 75 iters, 20 loads in flight
            float w[4][5];
            #pragma unroll
            for (int u = 0; u < 4; ++u)
                #pragma unroll
                for (int cc = 0; cc < 5; ++cc)
                    w[u][cc] = wp[cc][(size_t)(d + u) * DQKV_];
            float a[4][4];
            #pragma unroll
            for (int t = 0; t < 4; ++t)
                #pragma unroll
                for (int u = 0; u < 4; ++u) a[t][u] = arow[t * D_ + d + u];
            #pragma unroll
            for (int t = 0; t < 4; ++t)
                #pragma unroll
                for (int cc = 0; cc < 5; ++cc) {
                    float s = acc[t][cc];
                    #pragma unroll
                    for (int u = 0; u < 4; ++u) s += a[t][u] * w[u][cc];
                    acc[t][cc] = s;
                }
        }
        #pragma unroll
        for (int t = 0; t < 4; ++t) {
            int r = rg * 4 + t;
            if (r < nr) {
                float* orow = O + (size_t)(row0 + r) * KSTR;
                #pragma unroll
                for (int cc = 0; cc < 5; ++cc)
                    if (jc[cc] < DQKV_) orow[jc[cc]] = acc[t][cc];
            }
        }
        for (int i = tid; i < nr * 2; i += 256)      // zero row pad (read as f4)
            O[(size_t)(row0 + (i >> 1)) * KSTR + DQKV_ + (i & 1)] = 0.f;
        return;
    }

    // ---------------- scan path: half-row fill + exact top-10 ----------------
    const int sid  = b - NGEMM;
    const int row  = sid >> 1;
    const int half = sid & 1;
    const int lane = tid & 63, wave = tid >> 6;

    const float FILL = -18.420680743952367f;   // log(1e-8)
    {
        float4 f4 = make_float4(FILL, FILL, FILL, FILL);
        float4* o4 = (float4*)(out + (size_t)row * S_) + half * F4H;
        for (int i = tid; i < F4H; i += 256) o4[i] = f4;
    }

    float tv[K_]; int ti[K_];
    #pragma unroll
    for (int s = 0; s < K_; ++s) { tv[s] = -INFINITY; ti[s] = 0x7fffffff; }
    {
        const float4* p4 = (const float4*)(pred + (size_t)row * V_) + half * H4;
        const float4 NEG = make_float4(-INFINITY, -INFINITY, -INFINITY, -INFINITY);
        const int gb4 = half * H4;
        for (int batch = 0; batch < 3; ++batch) {     // 15 float4/thread, MLP 5
            float4 a[5]; int ib[5];
            #pragma unroll
            for (int u = 0; u < 5; ++u) {
                int i = tid + (batch * 5 + u) * 256;
                bool ok = i < H4;
                a[u]  = ok ? p4[i] : NEG;
                ib[u] = ok ? (gb4 + i) * 4 : 0x7ffffff0;
            }
            #pragma unroll
            for (int u = 0; u < 5; ++u) {
                float x = a[u].x, y = a[u].y, z = a[u].z, w = a[u].w;
                float m4 = fmaxf(fmaxf(x, y), fmaxf(z, w));
                if (!(m4 < tv[K_-1])) {               // quad skip vs own 10th
                    float vals[4] = {x, y, z, w};
                    #pragma unroll
                    for (int c = 0; c < 4; ++c) {
                        float val = vals[c];
                        int   idx = ib[u] + c;
                        if (better(val, idx, tv[K_-1], ti[K_-1])) {
                            tv[K_-1] = val; ti[K_-1] = idx;
                            #pragma unroll
                            for (int s = K_-1; s > 0; --s) {
                                if (better(tv[s], ti[s], tv[s-1], ti[s-1])) {
                                    float fx = tv[s]; tv[s] = tv[s-1]; tv[s-1] = fx;
                                    int   iy = ti[s]; ti[s] = ti[s-1]; ti[s-1] = iy;
                                }
                            }
                        }
                    }
                }
            }
        }
    }

    // per-wave top-10 (10 shfl-argmax passes), 4 waves
    for (int p = 0; p < K_; ++p) {
        float bv = tv[0]; int bi = ti[0];
        #pragma unroll
        for (int s = 1; s < K_; ++s)
            if (better(tv[s], ti[s], bv, bi)) { bv = tv[s]; bi = ti[s]; }
        #pragma unroll
        for (int off = 32; off; off >>= 1) {
            float ov = __shfl_xor(bv, off, 64);
            int   oi = __shfl_xor(bi, off, 64);
            if (better(ov, oi, bv, bi)) { bv = ov; bi = oi; }
        }
        if (lane == 0) { wcv[wave * K_ + p] = bv; wci[wave * K_ + p] = bi; }
        #pragma unroll
        for (int s = 0; s < K_; ++s)
            if (ti[s] == bi) tv[s] = -INFINITY;
    }
    __syncthreads();

    // wave 0: merge 40 candidates -> half top-10 -> ws (values + indices)
    if (wave == 0) {
        float cv = (lane < 40) ? wcv[lane] : -INFINITY;
        int   ci = (lane < 40) ? wci[lane] : 0x7fffffff;
        for (int p = 0; p < K_; ++p) {
            float bv = cv; int bi = ci;
            #pragma unroll
            for (int off = 32; off; off >>= 1) {
                float ov = __shfl_xor(bv, off, 64);
                int   oi = __shfl_xor(bi, off, 64);
                if (better(ov, oi, bv, bi)) { bv = ov; bi = oi; }
            }
            if (lane == 0) {
                wsv[(row * 2 + half) * K_ + p] = bv;
                wsi[(row * 2 + half) * K_ + p] = bi;
            }
            if (ci == bi) cv = -INFINITY;
        }
    }
}

// ============ Kernel 2: merge cands + neighbours + logits + softmax + scatter =
__global__ __launch_bounds__(NTA) void attn_kernel(
    const float* __restrict__ KC, const float* __restrict__ Qws,
    const int* __restrict__ nbt, const float* __restrict__ wsv,
    const int* __restrict__ wsi, float* __restrict__ out)
{
    const int row = blockIdx.x, tid = threadIdx.x;
    const int lane = tid & 63, wave = tid >> 6;
    __shared__ int   topg[K_];
    __shared__ __align__(16) float qsh[KSTR];
    __shared__ int   nidx[N_];
    __shared__ float lg[N_];
    __shared__ int   kills[N_];
    __shared__ float redA[8], redB[8];
    float* outrow = out + (size_t)row * S_;

    if (wave == 0) {
        // merge the two half top-10 lists (20 candidates) -> global top-10
        float cv = (lane < 2 * K_) ? wsv[row * 2 * K_ + lane] : -INFINITY;
        int   ci = (lane < 2 * K_) ? wsi[row * 2 * K_ + lane] : 0x7fffffff;
        for (int p = 0; p < K_; ++p) {
            float bv = cv; int bi = ci;
            #pragma unroll
            for (int off = 32; off; off >>= 1) {
                float ov = __shfl_xor(bv, off, 64);
                int   oi = __shfl_xor(bi, off, 64);
                if (better(ov, oi, bv, bi)) { bv = ov; bi = oi; }
            }
            if (lane == 0) topg[p] = bi;
            if (ci == bi) cv = -INFINITY;
        }
    } else if (tid >= 64 && tid < 64 + KSTR / 4) {    // 38 threads: q row as float4
        ((float4*)qsh)[tid - 64] = ((const float4*)(Qws + (size_t)row * KSTR))[tid - 64];
    } else if (tid >= 192) {                          // 320 threads: zero kill flags
        kills[tid - 192] = 0;
    }
    __syncthreads();                                   // BAR1

    if (tid < N_) nidx[tid] = nbt[topg[tid >> 5] * G_ + (tid & 31)];
    __syncthreads();                                   // BAR2

    // logits[n] = q . KC[nidx[n]] * ISC : 2 lanes per dot, 19 float4 each
    const float ISC = 0.08164965809277260327f;   // 1/sqrt(150)
    const float4* q4 = (const float4*)qsh;
    for (int s = tid; s < 2 * N_; s += NTA) {
        int n = s >> 1, h = s & 1;
        const float4* kc4 = (const float4*)(KC + (size_t)nidx[n] * KSTR) + h * 19;
        const float4* qq4 = q4 + h * 19;
        float acc = 0.f;
        #pragma unroll
        for (int cc = 0; cc < 19; ++cc) {
            float4 x = kc4[cc];
            float4 bq = qq4[cc];
            acc += x.x * bq.x + x.y * bq.y + x.z * bq.z + x.w * bq.w;
        }
        acc += __shfl_xor(acc, 1, 64);
        if (h == 0) lg[n] = acc * ISC;
    }
    __syncthreads();                                   // BAR3

    float v = (tid < N_) ? lg[tid] : -INFINITY;
    float m = v;
    #pragma unroll
    for (int off = 32; off; off >>= 1) m = fmaxf(m, __shfl_xor(m, off, 64));
    if (lane == 0) redA[wave] = m;
    __syncthreads();                                   // BAR4
    m = redA[0];
    #pragma unroll
    for (int w = 1; w < 8; ++w) m = fmaxf(m, redA[w]);

    float ss = (tid < N_) ? expf(v - m) : 0.f;
    #pragma unroll
    for (int off = 32; off; off >>= 1) ss += __shfl_xor(ss, off, 64);
    if (lane == 0) redB[wave] = ss;
    __syncthreads();                                   // BAR5
    float tot = redB[0];
    #pragma unroll
    for (int w = 1; w < 8; ++w) tot += redB[w];
    float lsum = logf(tot);

    // last-write-wins duplicate detection: 1280 chunk-scans of width 80
    for (int s = tid; s < 4 * N_; s += NTA) {
        int n = s >> 2, c = s & 3;
        int sidx = nidx[n];
        int clo = c * 80;
        int lo = (n + 1 > clo) ? n + 1 : clo;
        int hi = clo + 80;
        bool mt = false;
        #pragma unroll 4
        for (int n2 = lo; n2 < hi; ++n2) mt |= (nidx[n2] == sidx);
        if (mt) kills[n] = 1;
    }
    __syncthreads();                                   // BAR6

    if (tid < N_ && !kills[tid]) outrow[nidx[tid]] = (v - m) - lsum;
}

// ================= Fallback: fused single kernel (needs no ws) ===============
__global__ __launch_bounds__(NTS, 4) void selfatt_fused(
    const float* __restrict__ pred, const float* __restrict__ lc,
    const float* __restrict__ SC, const float* __restrict__ Wq,
    const float* __restrict__ Wk, const int* __restrict__ nbt,
    float* __restrict__ out)
{
    const int row = blockIdx.x, tid = threadIdx.x;
    const int lane = tid & 63, wave = tid >> 6;
    __shared__ float wcv[NWS * K_];
    __shared__ int   wci[NWS * K_];
    __shared__ int   topg[K_];
    __shared__ float lcs[D_];
    __shared__ float qs[DQKV_];
    __shared__ __align__(16) float qks[D_];
    __shared__ int   nidx[N_];
    __shared__ float lg[N_];
    __shared__ int   kills[N_];
    __shared__ float redA[NWS], redB[NWS];
    float* outrow = out + (size_t)row * S_;
    const float FILL = -18.420680743952367f;
    {
        float4 f4 = make_float4(FILL, FILL, FILL, FILL);
        float4* o4 = (float4*)outrow;
        #pragma unroll
        for (int k = 0; k < 7; ++k) { int i = tid + k * NTS; if (i < S4) o4[i] = f4; }
    }
    float tv[K_]; int ti[K_];
    #pragma unroll
    for (int s = 0; s < K_; ++s) { tv[s] = -INFINITY; ti[s] = 0x7fffffff; }
    {
        const float4* p4 = (const float4*)(pred + (size_t)row * V_);
        const float4 NEG = make_float4(-INFINITY, -INFINITY, -INFINITY, -INFINITY);
        float4 a[8]; int ib[8];
        #pragma unroll
        for (int u = 0; u < 8; ++u) {
            int i = tid + u * NTS;
            a[u]  = (i < V4) ? p4[i] : NEG;
            ib[u] = (i < V4) ? i * 4 : 0x7ffffff0;
        }
        #pragma unroll
        for (int u = 0; u < 8; ++u) {
            float x = a[u].x, y = a[u].y, z = a[u].z, w = a[u].w;
            float m4 = fmaxf(fmaxf(x, y), fmaxf(z, w));
            if (!(m4 < tv[K_-1])) {
                float vals[4] = {x, y, z, w};
                #pragma unroll
                for (int c = 0; c < 4; ++c) {
                    float val = vals[c];
                    int   idx = ib[u] + c;
                    if (better(val, idx, tv[K_-1], ti[K_-1])) {
                        tv[K_-1] = val; ti[K_-1] = idx;
                        #pragma unroll
                        for (int s = K_-1; s > 0; --s) {
                            if (better(tv[s], ti[s], tv[s-1], ti[s-1])) {
                                float fx = tv[s]; tv[s] = tv[s-1]; tv[s-1] = fx;
                                int   iy = ti[s]; ti[s] = ti[s-1]; ti[s-1] = iy;
                            }
                        }
                    }
                }
            }
        }
    }
    for (int p = 0; p < K_; ++p) {
        float bv = tv[0]; int bi = ti[0];
        #pragma unroll
        for (int s = 1; s < K_; ++s)
            if (better(tv[s], ti[s], bv, bi)) { bv = tv[s]; bi = ti[s]; }
        #pragma unroll
        for (int off = 32; off; off >>= 1) {
            float ov = __shfl_xor(bv, off, 64);
            int   oi = __shfl_xor(bi, off, 64);
            if (better(ov, oi, bv, bi)) { bv = ov; bi = oi; }
        }
        if (lane == 0) { wcv[wave * K_ + p] = bv; wci[wave * K_ + p] = bi; }
        #pragma unroll
        for (int s = 0; s < K_; ++s)
            if (ti[s] == bi) tv[s] = -INFINITY;
    }
    __syncthreads();
    if (wave == 0) {
        float c0v = wcv[lane],      c1v = wcv[64 + lane];
        int   c0i = wci[lane],      c1i = wci[64 + lane];
        float c2v = (lane < 32) ? wcv[128 + lane] : -INFINITY;
        int   c2i = (lane < 32) ? wci[128 + lane] : 0x7fffffff;
        for (int p = 0; p < K_; ++p) {
            float bv = c0v; int bi = c0i;
            if (better(c1v, c1i, bv, bi)) { bv = c1v; bi = c1i; }
            if (better(c2v, c2i, bv, bi)) { bv = c2v; bi = c2i; }
            #pragma unroll
            for (int off = 32; off; off >>= 1) {
                float ov = __shfl_xor(bv, off, 64);
                int   oi = __shfl_xor(bi, off, 64);
                if (better(ov, oi, bv, bi)) { bv = ov; bi = oi; }
            }
            if (lane == 0) topg[p] = bi;
            if (c0i == bi) c0v = -INFINITY;
            if (c1i == bi) c1v = -INFINITY;
            if (c2i == bi) c2v = -INFINITY;
        }
    }
    __syncthreads();
    if (tid < N_) { int g = topg[tid >> 5]; nidx[tid] = nbt[g * G_ + (tid & 31)]; }
    else if (tid < 2 * N_) kills[tid - N_] = 0;
    else if (tid >= 640 && tid < 640 + D_) lcs[tid - 640] = lc[(size_t)row * D_ + (tid - 640)];
    __syncthreads();
    if (tid < 600) {
        int j = tid >> 2, h = tid & 3;
        int d0 = h * 75;
        const float* wp = Wq + (size_t)d0 * DQKV_ + j;
        float acc = 0.f;
        #pragma unroll 5
        for (int dd = 0; dd < 75; ++dd) acc += lcs[d0 + dd] * wp[(size_t)dd * DQKV_];
        acc += __shfl_xor(acc, 1, 64);
        acc += __shfl_xor(acc, 2, 64);
        if (h == 0) qs[j] = acc;
    } else {
        int t0 = tid - 600;
        for (int s = t0; s < 4 * N_; s += 424) {
            int n = s >> 2, c = s & 3;
            int sidx = nidx[n];
            int clo = c * 80;
            int lo = (n + 1 > clo) ? n + 1 : clo;
            int hi = clo + 80;
            bool mt = false;
            #pragma unroll 4
            for (int n2 = lo; n2 < hi; ++n2) mt |= (nidx[n2] == sidx);
            if (mt) kills[n] = 1;
        }
    }
    __syncthreads();
    if (tid < 600) {
        int d = tid >> 1, h = tid & 1;
        int j0 = h * 75;
        const float* wrow = Wk + (size_t)d * DQKV_ + j0;
        float acc = 0.f;
        #pragma unroll 5
        for (int jj = 0; jj < 75; ++jj) acc += wrow[jj] * qs[j0 + jj];
        acc += __shfl_xor(acc, 1, 64);
        if (h == 0) qks[d] = acc;
    }
    __syncthreads();
    const float ISC = 0.08164965809277260327f;
    const float4* q4 = (const float4*)qks;
    for (int s = tid; s < 8 * N_; s += NTS) {
        int n = s >> 3, h = s & 7;
        const float4* sc4 = (const float4*)(SC + (size_t)nidx[n] * D_);
        int c0 = h * 9;
        float acc = 0.f;
        #pragma unroll
        for (int cc = 0; cc < 9; ++cc) {
            float4 a = sc4[c0 + cc];
            float4 b = q4[c0 + cc];
            acc += a.x * b.x + a.y * b.y + a.z * b.z + a.w * b.w;
        }
        if (h < 3) {
            float4 a = sc4[72 + h];
            float4 b = q4[72 + h];
            acc += a.x * b.x + a.y * b.y + a.z * b.z + a.w * b.w;
        }
        acc += __shfl_xor(acc, 1, 64);
        acc += __shfl_xor(acc, 2, 64);
        acc += __shfl_xor(acc, 4, 64);
        if (h == 0) lg[n] = acc * ISC;
    }
    __syncthreads();
    float v = (tid < N_) ? lg[tid] : -INFINITY;
    float m = v;
    #pragma unroll
    for (int off = 32; off; off >>= 1) m = fmaxf(m, __shfl_xor(m, off, 64));
    if (lane == 0) redA[wave] = m;
    __syncthreads();
    m = redA[0];
    #pragma unroll
    for (int w = 1; w < NWS; ++w) m = fmaxf(m, redA[w]);
    float e = (tid < N_) ? expf(v - m) : 0.f;
    float ss = e;
    #pragma unroll
    for (int off = 32; off; off >>= 1) ss += __shfl_xor(ss, off, 64);
    if (lane == 0) redB[wave] = ss;
    __syncthreads();
    float tot = redB[0];
    #pragma unroll
    for (int w = 1; w < NWS; ++w) tot += redB[w];
    float lsum = logf(tot);
    if (tid < N_ && !kills[tid]) outrow[nidx[tid]] = (v - m) - lsum;
}

extern "C" void kernel_launch(void* const* d_in, const int* in_sizes, int n_in,
                              void* d_out, int out_size, void* d_ws, size_t ws_size,
                              hipStream_t stream) {
    const float* pred = (const float*)d_in[0];
    const float* lc   = (const float*)d_in[1];
    const float* SC   = (const float*)d_in[2];
    const float* Wq   = (const float*)d_in[3];
    const float* Wk   = (const float*)d_in[4];
    const int*   nbt  = (const int*)d_in[5];
    float* out = (float*)d_out;

    const size_t nKC = (size_t)S_ * KSTR;
    const size_t nQ  = (size_t)T_ * B_ * KSTR;
    const size_t nCd = (size_t)T_ * B_ * 2 * K_;
    const size_t need = (nKC + nQ + nCd) * sizeof(float) + nCd * sizeof(int);
    if (ws_size >= need) {
        float* KC  = (float*)d_ws;
        float* Qws = KC + nKC;
        float* wsv = Qws + nQ;
        int*   wsi = (int*)(wsv + nCd);
        fused_stage1<<<dim3(NGEMM + NSCAN), dim3(256), 0, stream>>>(
            pred, lc, SC, Wq, Wk, out, KC, Qws, wsv, wsi);
        attn_kernel<<<dim3(T_ * B_), dim3(NTA), 0, stream>>>(
            KC, Qws, nbt, wsv, wsi, out);
    } else {
        selfatt_fused<<<dim3(T_ * B_), dim3(NTS), 0, stream>>>(
            pred, lc, SC, Wq, Wk, nbt, out);
    }
}

// Round 9
// 200.175 us; speedup vs baseline: 1.4585x; 1.2809x over previous
//
#include <hip/hip_runtime.h>
#include <math.h>

#define T_ 32
#define B_ 16
#define V_ 30000
#define V4 7500
#define D_ 300
#define DQKV_ 150
#define KSTR 152              // KC row stride (pad 150 -> 152 floats, 16B aligned)
#define K_ 10
#define G_ 32
#define N_ 320                // K*G
#define S_ 25000
#define S4 6250
#define GR2 16                // gemm rows per block
#define NBK2 1563             // ceil(25000/16)
#define NBQ2 32               // 512/16
#define NTS 1024              // scan threads
#define NTA 512               // attn threads
#define LCAP 4096             // candidate list capacity (expect ~680 for N(0,1))
#define UTH 0xC0000000u       // u-map(2.0f): accept x >= 2.0

__device__ __forceinline__ unsigned umap(float f) {
    unsigned b = __float_as_uint(f);
    unsigned mask = (unsigned)(((int)b) >> 31);      // 0xFFFFFFFF if negative
    return b ^ (mask | 0x80000000u);                 // ascending uint == ascending float
}
__device__ __forceinline__ bool better_u(unsigned au, int ai, unsigned bu, int bi) {
    return (au > bu) || (au == bu && ai < bi);       // higher val, ties -> lower idx
}

// ================= Kernel 1: KC = SC@Wk, Q = lc@Wq (spill-free) ==============
__global__ __launch_bounds__(256, 2) void gemm_kernel(
    const float* __restrict__ SC, const float* __restrict__ lc,
    const float* __restrict__ Wk, const float* __restrict__ Wq,
    float* __restrict__ KC, float* __restrict__ Qws)
{
    __shared__ __align__(16) float at[GR2 * D_];     // 19.2 KB
    const int b = blockIdx.x;
    const float* A; const float* Bw; float* O; int row0, M;
    if (b < NBK2) { A = SC; Bw = Wk; O = KC;  row0 = b * GR2;          M = S_; }
    else          { A = lc; Bw = Wq; O = Qws; row0 = (b - NBK2) * GR2; M = T_ * B_; }
    const int nr = (M - row0 < GR2) ? (M - row0) : GR2;

    const float4* a4 = (const float4*)(A + (size_t)row0 * D_);
    float4* t4 = (float4*)at;
    for (int i = threadIdx.x; i < nr * (D_ / 4); i += 256) t4[i] = a4[i];
    __syncthreads();

    const int cl = threadIdx.x & 31;       // col lane
    const int rg = threadIdx.x >> 5;       // row group (8 groups x 2 rows)
    int jc[5]; const float* wp[5];
    #pragma unroll
    for (int cc = 0; cc < 5; ++cc) {
        int j = cl + 32 * cc;
        jc[cc] = j;
        wp[cc] = Bw + (j < DQKV_ ? j : 0);           // clamp: loaded, never stored
    }
    float acc[2][5];
    #pragma unroll
    for (int t = 0; t < 2; ++t)
        #pragma unroll
        for (int cc = 0; cc < 5; ++cc) acc[t][cc] = 0.f;

    const float* ar0 = at + (rg * 2 + 0) * D_;
    const float* ar1 = at + (rg * 2 + 1) * D_;
    for (int d = 0; d < D_; d += 4) {                // 20 indep loads in flight
        float w[4][5];
        #pragma unroll
        for (int u = 0; u < 4; ++u)
            #pragma unroll
            for (int cc = 0; cc < 5; ++cc)
                w[u][cc] = wp[cc][(size_t)(d + u) * DQKV_];
        float a0[4], a1[4];
        #pragma unroll
        for (int u = 0; u < 4; ++u) { a0[u] = ar0[d + u]; a1[u] = ar1[d + u]; }
        #pragma unroll
        for (int u = 0; u < 4; ++u)
            #pragma unroll
            for (int cc = 0; cc < 5; ++cc) {
                acc[0][cc] += a0[u] * w[u][cc];
                acc[1][cc] += a1[u] * w[u][cc];
            }
    }
    #pragma unroll
    for (int t = 0; t < 2; ++t) {
        int r = rg * 2 + t;
        if (r < nr) {
            float* orow = O + (size_t)(row0 + r) * KSTR;
            #pragma unroll
            for (int cc = 0; cc < 5; ++cc)
                if (jc[cc] < DQKV_) orow[jc[cc]] = acc[t][cc];
        }
    }
    for (int i = threadIdx.x; i < nr * 2; i += 256)  // zero row pad (read as f4)
        O[(size_t)(row0 + (i >> 1)) * KSTR + DQKV_ + (i & 1)] = 0.f;
}

// ===== Kernel 2: fill + threshold-collect + exact top-10 select per row =====
__global__ __launch_bounds__(NTS, 2) void scan_kernel(
    const float* __restrict__ pred, float* __restrict__ out,
    int* __restrict__ wstop)
{
    const int row = blockIdx.x, tid = threadIdx.x;
    const int lane = tid & 63, wave = tid >> 6;
    __shared__ unsigned lu[LCAP];          // 16 KB candidate u-keys
    __shared__ int      li[LCAP];          // 16 KB candidate indices
    __shared__ int      cnt;

    if (tid == 0) cnt = 0;
    __syncthreads();

    // fill output row with log(1e-8)
    const float FILL = -18.420680743952367f;
    {
        float4 f4 = make_float4(FILL, FILL, FILL, FILL);
        float4* o4 = (float4*)(out + (size_t)row * S_);
        #pragma unroll
        for (int k = 0; k < 7; ++k) { int i = tid + k * NTS; if (i < S4) o4[i] = f4; }
    }

    // stream row: collect candidates with x >= 2.0 (u >= UTH); pure streaming
    {
        const float4* p4 = (const float4*)(pred + (size_t)row * V_);
        #pragma unroll
        for (int k = 0; k < 8; ++k) {
            int i = tid + k * NTS;
            if (i < V4) {
                float4 v = p4[i];
                unsigned u0 = umap(v.x), u1 = umap(v.y), u2 = umap(v.z), u3 = umap(v.w);
                int base = i * 4;
                if (u0 >= UTH) { int p = atomicAdd(&cnt, 1); if (p < LCAP) { lu[p] = u0; li[p] = base; } }
                if (u1 >= UTH) { int p = atomicAdd(&cnt, 1); if (p < LCAP) { lu[p] = u1; li[p] = base + 1; } }
                if (u2 >= UTH) { int p = atomicAdd(&cnt, 1); if (p < LCAP) { lu[p] = u2; li[p] = base + 2; } }
                if (u3 >= UTH) { int p = atomicAdd(&cnt, 1); if (p < LCAP) { lu[p] = u3; li[p] = base + 3; } }
            }
        }
    }
    __syncthreads();
    const int c = cnt;

    if (c >= K_ && c <= LCAP) {
        // main path: wave 0 selects exact top-10 from c candidates
        if (wave == 0) {
            for (int p = 0; p < K_; ++p) {
                unsigned bu = 0; int bi = 0x7fffffff;
                for (int s = lane; s < c; s += 64) {
                    unsigned uu = lu[s]; int ii = li[s];
                    if (better_u(uu, ii, bu, bi)) { bu = uu; bi = ii; }
                }
                #pragma unroll
                for (int off = 32; off; off >>= 1) {
                    unsigned ou = __shfl_xor(bu, off, 64);
                    int      oi = __shfl_xor(bi, off, 64);
                    if (better_u(ou, oi, bu, bi)) { bu = ou; bi = oi; }
                }
                if (lane == 0) wstop[row * K_ + p] = bi;
                // remove winner (unique by idx)
                for (int s = lane; s < c; s += 64)
                    if (li[s] == bi && lu[s] == bu) lu[s] = 0;
            }
        }
    } else {
        // exact fallback (never triggers for N(0,1) input): wave 0 re-scans row
        if (wave == 0) {
            unsigned tu[K_]; int tix[K_];
            #pragma unroll
            for (int s = 0; s < K_; ++s) { tu[s] = 0; tix[s] = 0x7fffffff; }
            const float* prow = pred + (size_t)row * V_;
            for (int i = lane; i < V_; i += 64) {
                unsigned u = umap(prow[i]);
                if (better_u(u, i, tu[K_-1], tix[K_-1])) {
                    tu[K_-1] = u; tix[K_-1] = i;
                    #pragma unroll
                    for (int s = K_-1; s > 0; --s)
                        if (better_u(tu[s], tix[s], tu[s-1], tix[s-1])) {
                            unsigned a = tu[s]; tu[s] = tu[s-1]; tu[s-1] = a;
                            int b2 = tix[s]; tix[s] = tix[s-1]; tix[s-1] = b2;
                        }
                }
            }
            for (int p = 0; p < K_; ++p) {
                unsigned bu = tu[0]; int bi = tix[0];
                #pragma unroll
                for (int s = 1; s < K_; ++s)
                    if (better_u(tu[s], tix[s], bu, bi)) { bu = tu[s]; bi = tix[s]; }
                #pragma unroll
                for (int off = 32; off; off >>= 1) {
                    unsigned ou = __shfl_xor(bu, off, 64);
                    int      oi = __shfl_xor(bi, off, 64);
                    if (better_u(ou, oi, bu, bi)) { bu = ou; bi = oi; }
                }
                if (lane == 0) wstop[row * K_ + p] = bi;
                #pragma unroll
                for (int s = 0; s < K_; ++s)
                    if (tix[s] == bi) tu[s] = 0;
            }
        }
    }
}

// ============ Kernel 3: neighbours + logits + softmax + scatter ==============
__global__ __launch_bounds__(NTA) void attn_kernel(
    const float* __restrict__ KC, const float* __restrict__ Qws,
    const int* __restrict__ nbt, const int* __restrict__ wstop,
    float* __restrict__ out)
{
    const int row = blockIdx.x, tid = threadIdx.x;
    const int lane = tid & 63, wave = tid >> 6;
    __shared__ int   topg[K_];
    __shared__ __align__(16) float qsh[KSTR];
    __shared__ int   nidx[N_];
    __shared__ float lg[N_];
    __shared__ int   kills[N_];
    __shared__ float redA[8], redB[8];
    float* outrow = out + (size_t)row * S_;

    if (tid < K_) topg[tid] = wstop[row * K_ + tid];
    else if (tid >= 64 && tid < 64 + KSTR / 4)        // 38 threads: q row as float4
        ((float4*)qsh)[tid - 64] = ((const float4*)(Qws + (size_t)row * KSTR))[tid - 64];
    else if (tid >= 192)                              // 320 threads: zero kill flags
        kills[tid - 192] = 0;
    __syncthreads();                                   // BAR1

    if (tid < N_) nidx[tid] = nbt[topg[tid >> 5] * G_ + (tid & 31)];
    __syncthreads();                                   // BAR2

    // logits[n] = q . KC[nidx[n]] * ISC : 2 lanes per dot, 19 float4 each
    const float ISC = 0.08164965809277260327f;   // 1/sqrt(150)
    const float4* q4 = (const float4*)qsh;
    for (int s = tid; s < 2 * N_; s += NTA) {
        int n = s >> 1, h = s & 1;
        const float4* kc4 = (const float4*)(KC + (size_t)nidx[n] * KSTR) + h * 19;
        const float4* qq4 = q4 + h * 19;
        float acc = 0.f;
        #pragma unroll
        for (int cc = 0; cc < 19; ++cc) {
            float4 x = kc4[cc];
            float4 bq = qq4[cc];
            acc += x.x * bq.x + x.y * bq.y + x.z * bq.z + x.w * bq.w;
        }
        acc += __shfl_xor(acc, 1, 64);
        if (h == 0) lg[n] = acc * ISC;
    }
    __syncthreads();                                   // BAR3

    float v = (tid < N_) ? lg[tid] : -INFINITY;
    float m = v;
    #pragma unroll
    for (int off = 32; off; off >>= 1) m = fmaxf(m, __shfl_xor(m, off, 64));
    if (lane == 0) redA[wave] = m;
    __syncthreads();                                   // BAR4
    m = redA[0];
    #pragma unroll
    for (int w = 1; w < 8; ++w) m = fmaxf(m, redA[w]);

    float ss = (tid < N_) ? expf(v - m) : 0.f;
    #pragma unroll
    for (int off = 32; off; off >>= 1) ss += __shfl_xor(ss, off, 64);
    if (lane == 0) redB[wave] = ss;
    __syncthreads();                                   // BAR5
    float tot = redB[0];
    #pragma unroll
    for (int w = 1; w < 8; ++w) tot += redB[w];
    float lsum = logf(tot);

    // last-write-wins duplicate detection: 1280 chunk-scans of width 80
    for (int s = tid; s < 4 * N_; s += NTA) {
        int n = s >> 2, cix = s & 3;
        int sidx = nidx[n];
        int clo = cix * 80;
        int lo = (n + 1 > clo) ? n + 1 : clo;
        int hi = clo + 80;
        bool mt = false;
        #pragma unroll 4
        for (int n2 = lo; n2 < hi; ++n2) mt |= (nidx[n2] == sidx);
        if (mt) kills[n] = 1;
    }
    __syncthreads();                                   // BAR6

    if (tid < N_ && !kills[tid]) outrow[nidx[tid]] = (v - m) - lsum;
}

// ================= Fallback: R5 fused single kernel (needs no ws) ============
#define NWS 16
__device__ __forceinline__ bool better(float av, int ai, float bv, int bi) {
    return (av > bv) || (av == bv && ai < bi);
}
__global__ __launch_bounds__(NTS, 4) void selfatt_fused(
    const float* __restrict__ pred, const float* __restrict__ lc,
    const float* __restrict__ SC, const float* __restrict__ Wq,
    const float* __restrict__ Wk, const int* __restrict__ nbt,
    float* __restrict__ out)
{
    const int row = blockIdx.x, tid = threadIdx.x;
    const int lane = tid & 63, wave = tid >> 6;
    __shared__ float wcv[NWS * K_];
    __shared__ int   wci[NWS * K_];
    __shared__ int   topg[K_];
    __shared__ float lcs[D_];
    __shared__ float qs[DQKV_];
    __shared__ __align__(16) float qks[D_];
    __shared__ int   nidx[N_];
    __shared__ float lg[N_];
    __shared__ int   kills[N_];
    __shared__ float redA[NWS], redB[NWS];
    float* outrow = out + (size_t)row * S_;
    const float FILL = -18.420680743952367f;
    {
        float4 f4 = make_float4(FILL, FILL, FILL, FILL);
        float4* o4 = (float4*)outrow;
        #pragma unroll
        for (int k = 0; k < 7; ++k) { int i = tid + k * NTS; if (i < S4) o4[i] = f4; }
    }
    float tv[K_]; int ti[K_];
    #pragma unroll
    for (int s = 0; s < K_; ++s) { tv[s] = -INFINITY; ti[s] = 0x7fffffff; }
    {
        const float4* p4 = (const float4*)(pred + (size_t)row * V_);
        const float4 NEG = make_float4(-INFINITY, -INFINITY, -INFINITY, -INFINITY);
        float4 a[8]; int ib[8];
        #pragma unroll
        for (int u = 0; u < 8; ++u) {
            int i = tid + u * NTS;
            a[u]  = (i < V4) ? p4[i] : NEG;
            ib[u] = (i < V4) ? i * 4 : 0x7ffffff0;
        }
        #pragma unroll
        for (int u = 0; u < 8; ++u) {
            float x = a[u].x, y = a[u].y, z = a[u].z, w = a[u].w;
            float m4 = fmaxf(fmaxf(x, y), fmaxf(z, w));
            if (!(m4 < tv[K_-1])) {
                float vals[4] = {x, y, z, w};
                #pragma unroll
                for (int cc = 0; cc < 4; ++cc) {
                    float val = vals[cc];
                    int   idx = ib[u] + cc;
                    if (better(val, idx, tv[K_-1], ti[K_-1])) {
                        tv[K_-1] = val; ti[K_-1] = idx;
                        #pragma unroll
                        for (int s = K_-1; s > 0; --s) {
                            if (better(tv[s], ti[s], tv[s-1], ti[s-1])) {
                                float fx = tv[s]; tv[s] = tv[s-1]; tv[s-1] = fx;
                                int   iy = ti[s]; ti[s] = ti[s-1]; ti[s-1] = iy;
                            }
                        }
                    }
                }
            }
        }
    }
    for (int p = 0; p < K_; ++p) {
        float bv = tv[0]; int bi = ti[0];
        #pragma unroll
        for (int s = 1; s < K_; ++s)
            if (better(tv[s], ti[s], bv, bi)) { bv = tv[s]; bi = ti[s]; }
        #pragma unroll
        for (int off = 32; off; off >>= 1) {
            float ov = __shfl_xor(bv, off, 64);
            int   oi = __shfl_xor(bi, off, 64);
            if (better(ov, oi, bv, bi)) { bv = ov; bi = oi; }
        }
        if (lane == 0) { wcv[wave * K_ + p] = bv; wci[wave * K_ + p] = bi; }
        #pragma unroll
        for (int s = 0; s < K_; ++s)
            if (ti[s] == bi) tv[s] = -INFINITY;
    }
    __syncthreads();
    if (wave == 0) {
        float c0v = wcv[lane],      c1v = wcv[64 + lane];
        int   c0i = wci[lane],      c1i = wci[64 + lane];
        float c2v = (lane < 32) ? wcv[128 + lane] : -INFINITY;
        int   c2i = (lane < 32) ? wci[128 + lane] : 0x7fffffff;
        for (int p = 0; p < K_; ++p) {
            float bv = c0v; int bi = c0i;
            if (better(c1v, c1i, bv, bi)) { bv = c1v; bi = c1i; }
            if (better(c2v, c2i, bv, bi)) { bv = c2v; bi = c2i; }
            #pragma unroll
            for (int off = 32; off; off >>= 1) {
                float ov = __shfl_xor(bv, off, 64);
                int   oi = __shfl_xor(bi, off, 64);
                if (better(ov, oi, bv, bi)) { bv = ov; bi = oi; }
            }
            if (lane == 0) topg[p] = bi;
            if (c0i == bi) c0v = -INFINITY;
            if (c1i == bi) c1v = -INFINITY;
            if (c2i == bi) c2v = -INFINITY;
        }
    }
    __syncthreads();
    if (tid < N_) { int g = topg[tid >> 5]; nidx[tid] = nbt[g * G_ + (tid & 31)]; }
    else if (tid < 2 * N_) kills[tid - N_] = 0;
    else if (tid >= 640 && tid < 640 + D_) lcs[tid - 640] = lc[(size_t)row * D_ + (tid - 640)];
    __syncthreads();
    if (tid < 600) {
        int j = tid >> 2, h = tid & 3;
        int d0 = h * 75;
        const float* wp = Wq + (size_t)d0 * DQKV_ + j;
        float acc = 0.f;
        #pragma unroll 5
        for (int dd = 0; dd < 75; ++dd) acc += lcs[d0 + dd] * wp[(size_t)dd * DQKV_];
        acc += __shfl_xor(acc, 1, 64);
        acc += __shfl_xor(acc, 2, 64);
        if (h == 0) qs[j] = acc;
    } else {
        int t0 = tid - 600;
        for (int s = t0; s < 4 * N_; s += 424) {
            int n = s >> 2, cc = s & 3;
            int sidx = nidx[n];
            int clo = cc * 80;
            int lo = (n + 1 > clo) ? n + 1 : clo;
            int hi = clo + 80;
            bool mt = false;
            #pragma unroll 4
            for (int n2 = lo; n2 < hi; ++n2) mt |= (nidx[n2] == sidx);
            if (mt) kills[n] = 1;
        }
    }
    __syncthreads();
    if (tid < 600) {
        int d = tid >> 1, h = tid & 1;
        int j0 = h * 75;
        const float* wrow = Wk + (size_t)d * DQKV_ + j0;
        float acc = 0.f;
        #pragma unroll 5
        for (int jj = 0; jj < 75; ++jj) acc += wrow[jj] * qs[j0 + jj];
        acc += __shfl_xor(acc, 1, 64);
        if (h == 0) qks[d] = acc;
    }
    __syncthreads();
    const float ISC = 0.08164965809277260327f;
    const float4* q4 = (const float4*)qks;
    for (int s = tid; s < 8 * N_; s += NTS) {
        int n = s >> 3, h = s & 7;
        const float4* sc4 = (const float4*)(SC + (size_t)nidx[n] * D_);
        int c0 = h * 9;
        float acc = 0.f;
        #pragma unroll
        for (int cc = 0; cc < 9; ++cc) {
            float4 a = sc4[c0 + cc];
            float4 b = q4[c0 + cc];
            acc += a.x * b.x + a.y * b.y + a.z * b.z + a.w * b.w;
        }
        if (h < 3) {
            float4 a = sc4[72 + h];
            float4 b = q4[72 + h];
            acc += a.x * b.x + a.y * b.y + a.z * b.z + a.w * b.w;
        }
        acc += __shfl_xor(acc, 1, 64);
        acc += __shfl_xor(acc, 2, 64);
        acc += __shfl_xor(acc, 4, 64);
        if (h == 0) lg[n] = acc * ISC;
    }
    __syncthreads();
    float v = (tid < N_) ? lg[tid] : -INFINITY;
    float m = v;
    #pragma unroll
    for (int off = 32; off; off >>= 1) m = fmaxf(m, __shfl_xor(m, off, 64));
    if (lane == 0) redA[wave] = m;
    __syncthreads();
    m = redA[0];
    #pragma unroll
    for (int w = 1; w < NWS; ++w) m = fmaxf(m, redA[w]);
    float e = (tid < N_) ? expf(v - m) : 0.f;
    float ss = e;
    #pragma unroll
    for (int off = 32; off; off >>= 1) ss += __shfl_xor(ss, off, 64);
    if (lane == 0) redB[wave] = ss;
    __syncthreads();
    float tot = redB[0];
    #pragma unroll
    for (int w = 1; w < NWS; ++w) tot += redB[w];
    float lsum = logf(tot);
    if (tid < N_ && !kills[tid]) outrow[nidx[tid]] = (v - m) - lsum;
}

extern "C" void kernel_launch(void* const* d_in, const int* in_sizes, int n_in,
                              void* d_out, int out_size, void* d_ws, size_t ws_size,
                              hipStream_t stream) {
    const float* pred = (const float*)d_in[0];
    const float* lc   = (const float*)d_in[1];
    const float* SC   = (const float*)d_in[2];
    const float* Wq   = (const float*)d_in[3];
    const float* Wk   = (const float*)d_in[4];
    const int*   nbt  = (const int*)d_in[5];
    float* out = (float*)d_out;

    const size_t nKC = (size_t)S_ * KSTR;
    const size_t nQ  = (size_t)T_ * B_ * KSTR;
    const size_t need = (nKC + nQ) * sizeof(float) + (size_t)T_ * B_ * K_ * sizeof(int);
    if (ws_size >= need) {
        float* KC    = (float*)d_ws;
        float* Qws   = KC + nKC;
        int*   wstop = (int*)(Qws + nQ);
        gemm_kernel<<<dim3(NBK2 + NBQ2), dim3(256), 0, stream>>>(SC, lc, Wk, Wq, KC, Qws);
        scan_kernel<<<dim3(T_ * B_), dim3(NTS), 0, stream>>>(pred, out, wstop);
        attn_kernel<<<dim3(T_ * B_), dim3(NTA), 0, stream>>>(KC, Qws, nbt, wstop, out);
    } else {
        selfatt_fused<<<dim3(T_ * B_), dim3(NTS), 0, stream>>>(
            pred, lc, SC, Wq, Wk, nbt, out);
    }
}

// Round 10
// 160.024 us; speedup vs baseline: 1.8244x; 1.2509x over previous
//
#include <hip/hip_runtime.h>
#include <math.h>

#define T_ 32
#define B_ 16
#define V_ 30000
#define V4 7500
#define D_ 300
#define DQKV_ 150
#define KSTR 152              // KC row stride (pad 150 -> 152 floats, 16B aligned)
#define K_ 10
#define G_ 32
#define N_ 320                // K*G
#define S_ 25000
#define S4 6250
#define GRW 64                // gemm rows per block (1 per lane)
#define APAD 301              // LDS row pitch: 13*lane mod 32 -> conflict-free
#define NBK3 391              // ceil(25000/64)
#define NBQ3 8                // 512/64
#define NTS 1024              // scan threads
#define NTA 512               // attn threads
#define LCAP 4096             // candidate list capacity (expect ~680 for N(0,1))
#define UTH 0xC0000000u       // u-map(2.0f): accept x >= 2.0

__device__ __forceinline__ unsigned umap(float f) {
    unsigned b = __float_as_uint(f);
    unsigned mask = (unsigned)(((int)b) >> 31);      // 0xFFFFFFFF if negative
    return b ^ (mask | 0x80000000u);                 // ascending uint == ascending float
}
__device__ __forceinline__ bool better_u(unsigned au, int ai, unsigned bu, int bi) {
    return (au > bu) || (au == bu && ai < bi);       // higher val, ties -> lower idx
}

// ======= Kernel 1: KC = SC@Wk, Q = lc@Wq — row-per-lane, scalar B-operand ====
// Wave w owns cols [c0, c0+38) with c0 in {0,38,76,112} (2-col overlap is a
// benign duplicate write of identical values). B loads are wave-uniform ->
// scalar (SGPR) loads; A from LDS; inner loop = pure v_fmac v,s,v.
__global__ __launch_bounds__(256, 2) void gemm_kernel(
    const float* __restrict__ SC, const float* __restrict__ lc,
    const float* __restrict__ Wk, const float* __restrict__ Wq,
    float* __restrict__ KC, float* __restrict__ Qws)
{
    __shared__ float at[GRW * APAD];                 // 77.06 KB
    const int b = blockIdx.x;
    const float* A; const float* Bw; float* O; int row0, M;
    if (b < NBK3) { A = SC; Bw = Wk; O = KC;  row0 = b * GRW;          M = S_; }
    else          { A = lc; Bw = Wq; O = Qws; row0 = (b - NBK3) * GRW; M = T_ * B_; }
    const int nr = (M - row0 < GRW) ? (M - row0) : GRW;

    // stage A tile: coalesced global float4 -> 4x b32 LDS (conflict-free)
    {
        const float4* a4 = (const float4*)(A + (size_t)row0 * D_);
        for (int i = threadIdx.x; i < nr * (D_ / 4); i += 256) {
            int r = i / (D_ / 4), q = i - r * (D_ / 4);
            float4 v = a4[i];
            float* dst = at + r * APAD + q * 4;
            dst[0] = v.x; dst[1] = v.y; dst[2] = v.z; dst[3] = v.w;
        }
    }
    __syncthreads();

    const int lane = threadIdx.x & 63;               // = row within tile
    const int wv   = threadIdx.x >> 6;
    const int c0   = __builtin_amdgcn_readfirstlane(wv < 3 ? wv * 38 : DQKV_ - 38);

    float acc[38];
    #pragma unroll
    for (int cc = 0; cc < 38; ++cc) acc[cc] = 0.f;

    const float* arow = at + lane * APAD;
    for (int d = 0; d < D_; ++d) {
        float a = arow[d];                           // ds_read_b32, 32 banks
        const float* wrow = Bw + d * DQKV_ + c0;     // wave-uniform -> s_load
        #pragma unroll
        for (int cc = 0; cc < 38; ++cc)
            acc[cc] += a * wrow[cc];                 // v_fmac v, s, v
    }

    if (lane < nr) {
        float* orow = O + (size_t)(row0 + lane) * KSTR + c0;
        #pragma unroll
        for (int cc = 0; cc < 19; ++cc)              // 19 x float2 (c0 even)
            *(float2*)(orow + 2 * cc) = make_float2(acc[2 * cc], acc[2 * cc + 1]);
    }
    // zero the 2-float row pad (attn reads rows as 38 float4)
    for (int i = threadIdx.x; i < nr * 2; i += 256)
        O[(size_t)(row0 + (i >> 1)) * KSTR + DQKV_ + (i & 1)] = 0.f;
}

// ===== Kernel 2: fill + threshold-collect + exact top-10 select per row =====
__global__ __launch_bounds__(NTS, 2) void scan_kernel(
    const float* __restrict__ pred, float* __restrict__ out,
    int* __restrict__ wstop)
{
    const int row = blockIdx.x, tid = threadIdx.x;
    const int lane = tid & 63, wave = tid >> 6;
    __shared__ unsigned lu[LCAP];          // 16 KB candidate u-keys
    __shared__ int      li[LCAP];          // 16 KB candidate indices
    __shared__ int      cnt;

    if (tid == 0) cnt = 0;
    __syncthreads();

    // fill output row with log(1e-8)
    const float FILL = -18.420680743952367f;
    {
        float4 f4 = make_float4(FILL, FILL, FILL, FILL);
        float4* o4 = (float4*)(out + (size_t)row * S_);
        #pragma unroll
        for (int k = 0; k < 7; ++k) { int i = tid + k * NTS; if (i < S4) o4[i] = f4; }
    }

    // stream row: collect candidates with x >= 2.0 (u >= UTH); pure streaming
    {
        const float4* p4 = (const float4*)(pred + (size_t)row * V_);
        #pragma unroll
        for (int k = 0; k < 8; ++k) {
            int i = tid + k * NTS;
            if (i < V4) {
                float4 v = p4[i];
                unsigned u0 = umap(v.x), u1 = umap(v.y), u2 = umap(v.z), u3 = umap(v.w);
                int base = i * 4;
                if (u0 >= UTH) { int p = atomicAdd(&cnt, 1); if (p < LCAP) { lu[p] = u0; li[p] = base; } }
                if (u1 >= UTH) { int p = atomicAdd(&cnt, 1); if (p < LCAP) { lu[p] = u1; li[p] = base + 1; } }
                if (u2 >= UTH) { int p = atomicAdd(&cnt, 1); if (p < LCAP) { lu[p] = u2; li[p] = base + 2; } }
                if (u3 >= UTH) { int p = atomicAdd(&cnt, 1); if (p < LCAP) { lu[p] = u3; li[p] = base + 3; } }
            }
        }
    }
    __syncthreads();
    const int c = cnt;

    if (c >= K_ && c <= LCAP) {
        // main path: wave 0 selects exact top-10 from c candidates
        if (wave == 0) {
            for (int p = 0; p < K_; ++p) {
                unsigned bu = 0; int bi = 0x7fffffff;
                for (int s = lane; s < c; s += 64) {
                    unsigned uu = lu[s]; int ii = li[s];
                    if (better_u(uu, ii, bu, bi)) { bu = uu; bi = ii; }
                }
                #pragma unroll
                for (int off = 32; off; off >>= 1) {
                    unsigned ou = __shfl_xor(bu, off, 64);
                    int      oi = __shfl_xor(bi, off, 64);
                    if (better_u(ou, oi, bu, bi)) { bu = ou; bi = oi; }
                }
                if (lane == 0) wstop[row * K_ + p] = bi;
                // remove winner (unique by idx)
                for (int s = lane; s < c; s += 64)
                    if (li[s] == bi && lu[s] == bu) lu[s] = 0;
            }
        }
    } else {
        // exact fallback (never triggers for N(0,1) input): wave 0 re-scans row
        if (wave == 0) {
            unsigned tu[K_]; int tix[K_];
            #pragma unroll
            for (int s = 0; s < K_; ++s) { tu[s] = 0; tix[s] = 0x7fffffff; }
            const float* prow = pred + (size_t)row * V_;
            for (int i = lane; i < V_; i += 64) {
                unsigned u = umap(prow[i]);
                if (better_u(u, i, tu[K_-1], tix[K_-1])) {
                    tu[K_-1] = u; tix[K_-1] = i;
                    #pragma unroll
                    for (int s = K_-1; s > 0; --s)
                        if (better_u(tu[s], tix[s], tu[s-1], tix[s-1])) {
                            unsigned a = tu[s]; tu[s] = tu[s-1]; tu[s-1] = a;
                            int b2 = tix[s]; tix[s] = tix[s-1]; tix[s-1] = b2;
                        }
                }
            }
            for (int p = 0; p < K_; ++p) {
                unsigned bu = tu[0]; int bi = tix[0];
                #pragma unroll
                for (int s = 1; s < K_; ++s)
                    if (better_u(tu[s], tix[s], bu, bi)) { bu = tu[s]; bi = tix[s]; }
                #pragma unroll
                for (int off = 32; off; off >>= 1) {
                    unsigned ou = __shfl_xor(bu, off, 64);
                    int      oi = __shfl_xor(bi, off, 64);
                    if (better_u(ou, oi, bu, bi)) { bu = ou; bi = oi; }
                }
                if (lane == 0) wstop[row * K_ + p] = bi;
                #pragma unroll
                for (int s = 0; s < K_; ++s)
                    if (tix[s] == bi) tu[s] = 0;
            }
        }
    }
}

// ============ Kernel 3: neighbours + logits + softmax + scatter ==============
__global__ __launch_bounds__(NTA) void attn_kernel(
    const float* __restrict__ KC, const float* __restrict__ Qws,
    const int* __restrict__ nbt, const int* __restrict__ wstop,
    float* __restrict__ out)
{
    const int row = blockIdx.x, tid = threadIdx.x;
    const int lane = tid & 63, wave = tid >> 6;
    __shared__ int   topg[K_];
    __shared__ __align__(16) float qsh[KSTR];
    __shared__ int   nidx[N_];
    __shared__ float lg[N_];
    __shared__ int   kills[N_];
    __shared__ float redA[8], redB[8];
    float* outrow = out + (size_t)row * S_;

    if (tid < K_) topg[tid] = wstop[row * K_ + tid];
    else if (tid >= 64 && tid < 64 + KSTR / 4)        // 38 threads: q row as float4
        ((float4*)qsh)[tid - 64] = ((const float4*)(Qws + (size_t)row * KSTR))[tid - 64];
    else if (tid >= 192)                              // 320 threads: zero kill flags
        kills[tid - 192] = 0;
    __syncthreads();                                   // BAR1

    if (tid < N_) nidx[tid] = nbt[topg[tid >> 5] * G_ + (tid & 31)];
    __syncthreads();                                   // BAR2

    // logits[n] = q . KC[nidx[n]] * ISC : 2 lanes per dot, 19 float4 each
    const float ISC = 0.08164965809277260327f;   // 1/sqrt(150)
    const float4* q4 = (const float4*)qsh;
    for (int s = tid; s < 2 * N_; s += NTA) {
        int n = s >> 1, h = s & 1;
        const float4* kc4 = (const float4*)(KC + (size_t)nidx[n] * KSTR) + h * 19;
        const float4* qq4 = q4 + h * 19;
        float acc = 0.f;
        #pragma unroll
        for (int cc = 0; cc < 19; ++cc) {
            float4 x = kc4[cc];
            float4 bq = qq4[cc];
            acc += x.x * bq.x + x.y * bq.y + x.z * bq.z + x.w * bq.w;
        }
        acc += __shfl_xor(acc, 1, 64);
        if (h == 0) lg[n] = acc * ISC;
    }
    __syncthreads();                                   // BAR3

    float v = (tid < N_) ? lg[tid] : -INFINITY;
    float m = v;
    #pragma unroll
    for (int off = 32; off; off >>= 1) m = fmaxf(m, __shfl_xor(m, off, 64));
    if (lane == 0) redA[wave] = m;
    __syncthreads();                                   // BAR4
    m = redA[0];
    #pragma unroll
    for (int w = 1; w < 8; ++w) m = fmaxf(m, redA[w]);

    float ss = (tid < N_) ? expf(v - m) : 0.f;
    #pragma unroll
    for (int off = 32; off; off >>= 1) ss += __shfl_xor(ss, off, 64);
    if (lane == 0) redB[wave] = ss;
    __syncthreads();                                   // BAR5
    float tot = redB[0];
    #pragma unroll
    for (int w = 1; w < 8; ++w) tot += redB[w];
    float lsum = logf(tot);

    // last-write-wins duplicate detection: 1280 chunk-scans of width 80
    for (int s = tid; s < 4 * N_; s += NTA) {
        int n = s >> 2, cix = s & 3;
        int sidx = nidx[n];
        int clo = cix * 80;
        int lo = (n + 1 > clo) ? n + 1 : clo;
        int hi = clo + 80;
        bool mt = false;
        #pragma unroll 4
        for (int n2 = lo; n2 < hi; ++n2) mt |= (nidx[n2] == sidx);
        if (mt) kills[n] = 1;
    }
    __syncthreads();                                   // BAR6

    if (tid < N_ && !kills[tid]) outrow[nidx[tid]] = (v - m) - lsum;
}

// ================= Fallback: fused single kernel (needs no ws) ===============
#define NWS 16
__device__ __forceinline__ bool better(float av, int ai, float bv, int bi) {
    return (av > bv) || (av == bv && ai < bi);
}
__global__ __launch_bounds__(NTS, 4) void selfatt_fused(
    const float* __restrict__ pred, const float* __restrict__ lc,
    const float* __restrict__ SC, const float* __restrict__ Wq,
    const float* __restrict__ Wk, const int* __restrict__ nbt,
    float* __restrict__ out)
{
    const int row = blockIdx.x, tid = threadIdx.x;
    const int lane = tid & 63, wave = tid >> 6;
    __shared__ float wcv[NWS * K_];
    __shared__ int   wci[NWS * K_];
    __shared__ int   topg[K_];
    __shared__ float lcs[D_];
    __shared__ float qs[DQKV_];
    __shared__ __align__(16) float qks[D_];
    __shared__ int   nidx[N_];
    __shared__ float lg[N_];
    __shared__ int   kills[N_];
    __shared__ float redA[NWS], redB[NWS];
    float* outrow = out + (size_t)row * S_;
    const float FILL = -18.420680743952367f;
    {
        float4 f4 = make_float4(FILL, FILL, FILL, FILL);
        float4* o4 = (float4*)outrow;
        #pragma unroll
        for (int k = 0; k < 7; ++k) { int i = tid + k * NTS; if (i < S4) o4[i] = f4; }
    }
    float tv[K_]; int ti[K_];
    #pragma unroll
    for (int s = 0; s < K_; ++s) { tv[s] = -INFINITY; ti[s] = 0x7fffffff; }
    {
        const float4* p4 = (const float4*)(pred + (size_t)row * V_);
        const float4 NEG = make_float4(-INFINITY, -INFINITY, -INFINITY, -INFINITY);
        float4 a[8]; int ib[8];
        #pragma unroll
        for (int u = 0; u < 8; ++u) {
            int i = tid + u * NTS;
            a[u]  = (i < V4) ? p4[i] : NEG;
            ib[u] = (i < V4) ? i * 4 : 0x7ffffff0;
        }
        #pragma unroll
        for (int u = 0; u < 8; ++u) {
            float x = a[u].x, y = a[u].y, z = a[u].z, w = a[u].w;
            float m4 = fmaxf(fmaxf(x, y), fmaxf(z, w));
            if (!(m4 < tv[K_-1])) {
                float vals[4] = {x, y, z, w};
                #pragma unroll
                for (int cc = 0; cc < 4; ++cc) {
                    float val = vals[cc];
                    int   idx = ib[u] + cc;
                    if (better(val, idx, tv[K_-1], ti[K_-1])) {
                        tv[K_-1] = val; ti[K_-1] = idx;
                        #pragma unroll
                        for (int s = K_-1; s > 0; --s) {
                            if (better(tv[s], ti[s], tv[s-1], ti[s-1])) {
                                float fx = tv[s]; tv[s] = tv[s-1]; tv[s-1] = fx;
                                int   iy = ti[s]; ti[s] = ti[s-1]; ti[s-1] = iy;
                            }
                        }
                    }
                }
            }
        }
    }
    for (int p = 0; p < K_; ++p) {
        float bv = tv[0]; int bi = ti[0];
        #pragma unroll
        for (int s = 1; s < K_; ++s)
            if (better(tv[s], ti[s], bv, bi)) { bv = tv[s]; bi = ti[s]; }
        #pragma unroll
        for (int off = 32; off; off >>= 1) {
            float ov = __shfl_xor(bv, off, 64);
            int   oi = __shfl_xor(bi, off, 64);
            if (better(ov, oi, bv, bi)) { bv = ov; bi = oi; }
        }
        if (lane == 0) { wcv[wave * K_ + p] = bv; wci[wave * K_ + p] = bi; }
        #pragma unroll
        for (int s = 0; s < K_; ++s)
            if (ti[s] == bi) tv[s] = -INFINITY;
    }
    __syncthreads();
    if (wave == 0) {
        float c0v = wcv[lane],      c1v = wcv[64 + lane];
        int   c0i = wci[lane],      c1i = wci[64 + lane];
        float c2v = (lane < 32) ? wcv[128 + lane] : -INFINITY;
        int   c2i = (lane < 32) ? wci[128 + lane] : 0x7fffffff;
        for (int p = 0; p < K_; ++p) {
            float bv = c0v; int bi = c0i;
            if (better(c1v, c1i, bv, bi)) { bv = c1v; bi = c1i; }
            if (better(c2v, c2i, bv, bi)) { bv = c2v; bi = c2i; }
            #pragma unroll
            for (int off = 32; off; off >>= 1) {
                float ov = __shfl_xor(bv, off, 64);
                int   oi = __shfl_xor(bi, off, 64);
                if (better(ov, oi, bv, bi)) { bv = ov; bi = oi; }
            }
            if (lane == 0) topg[p] = bi;
            if (c0i == bi) c0v = -INFINITY;
            if (c1i == bi) c1v = -INFINITY;
            if (c2i == bi) c2v = -INFINITY;
        }
    }
    __syncthreads();
    if (tid < N_) { int g = topg[tid >> 5]; nidx[tid] = nbt[g * G_ + (tid & 31)]; }
    else if (tid < 2 * N_) kills[tid - N_] = 0;
    else if (tid >= 640 && tid < 640 + D_) lcs[tid - 640] = lc[(size_t)row * D_ + (tid - 640)];
    __syncthreads();
    if (tid < 600) {
        int j = tid >> 2, h = tid & 3;
        int d0 = h * 75;
        const float* wp = Wq + (size_t)d0 * DQKV_ + j;
        float acc = 0.f;
        #pragma unroll 5
        for (int dd = 0; dd < 75; ++dd) acc += lcs[d0 + dd] * wp[(size_t)dd * DQKV_];
        acc += __shfl_xor(acc, 1, 64);
        acc += __shfl_xor(acc, 2, 64);
        if (h == 0) qs[j] = acc;
    } else {
        int t0 = tid - 600;
        for (int s = t0; s < 4 * N_; s += 424) {
            int n = s >> 2, cc = s & 3;
            int sidx = nidx[n];
            int clo = cc * 80;
            int lo = (n + 1 > clo) ? n + 1 : clo;
            int hi = clo + 80;
            bool mt = false;
            #pragma unroll 4
            for (int n2 = lo; n2 < hi; ++n2) mt |= (nidx[n2] == sidx);
            if (mt) kills[n] = 1;
        }
    }
    __syncthreads();
    if (tid < 600) {
        int d = tid >> 1, h = tid & 1;
        int j0 = h * 75;
        const float* wrow = Wk + (size_t)d * DQKV_ + j0;
        float acc = 0.f;
        #pragma unroll 5
        for (int jj = 0; jj < 75; ++jj) acc += wrow[jj] * qs[j0 + jj];
        acc += __shfl_xor(acc, 1, 64);
        if (h == 0) qks[d] = acc;
    }
    __syncthreads();
    const float ISC = 0.08164965809277260327f;
    const float4* q4 = (const float4*)qks;
    for (int s = tid; s < 8 * N_; s += NTS) {
        int n = s >> 3, h = s & 7;
        const float4* sc4 = (const float4*)(SC + (size_t)nidx[n] * D_);
        int c0 = h * 9;
        float acc = 0.f;
        #pragma unroll
        for (int cc = 0; cc < 9; ++cc) {
            float4 a = sc4[c0 + cc];
            float4 b = q4[c0 + cc];
            acc += a.x * b.x + a.y * b.y + a.z * b.z + a.w * b.w;
        }
        if (h < 3) {
            float4 a = sc4[72 + h];
            float4 b = q4[72 + h];
            acc += a.x * b.x + a.y * b.y + a.z * b.z + a.w * b.w;
        }
        acc += __shfl_xor(acc, 1, 64);
        acc += __shfl_xor(acc, 2, 64);
        acc += __shfl_xor(acc, 4, 64);
        if (h == 0) lg[n] = acc * ISC;
    }
    __syncthreads();
    float v = (tid < N_) ? lg[tid] : -INFINITY;
    float m = v;
    #pragma unroll
    for (int off = 32; off; off >>= 1) m = fmaxf(m, __shfl_xor(m, off, 64));
    if (lane == 0) redA[wave] = m;
    __syncthreads();
    m = redA[0];
    #pragma unroll
    for (int w = 1; w < NWS; ++w) m = fmaxf(m, redA[w]);
    float e = (tid < N_) ? expf(v - m) : 0.f;
    float ss = e;
    #pragma unroll
    for (int off = 32; off; off >>= 1) ss += __shfl_xor(ss, off, 64);
    if (lane == 0) redB[wave] = ss;
    __syncthreads();
    float tot = redB[0];
    #pragma unroll
    for (int w = 1; w < NWS; ++w) tot += redB[w];
    float lsum = logf(tot);
    if (tid < N_ && !kills[tid]) outrow[nidx[tid]] = (v - m) - lsum;
}

extern "C" void kernel_launch(void* const* d_in, const int* in_sizes, int n_in,
                              void* d_out, int out_size, void* d_ws, size_t ws_size,
                              hipStream_t stream) {
    const float* pred = (const float*)d_in[0];
    const float* lc   = (const float*)d_in[1];
    const float* SC   = (const float*)d_in[2];
    const float* Wq   = (const float*)d_in[3];
    const float* Wk   = (const float*)d_in[4];
    const int*   nbt  = (const int*)d_in[5];
    float* out = (float*)d_out;

    const size_t nKC = (size_t)S_ * KSTR;
    const size_t nQ  = (size_t)T_ * B_ * KSTR;
    const size_t need = (nKC + nQ) * sizeof(float) + (size_t)T_ * B_ * K_ * sizeof(int);
    if (ws_size >= need) {
        float* KC    = (float*)d_ws;
        float* Qws   = KC + nKC;
        int*   wstop = (int*)(Qws + nQ);
        gemm_kernel<<<dim3(NBK3 + NBQ3), dim3(256), 0, stream>>>(SC, lc, Wk, Wq, KC, Qws);
        scan_kernel<<<dim3(T_ * B_), dim3(NTS), 0, stream>>>(pred, out, wstop);
        attn_kernel<<<dim3(T_ * B_), dim3(NTA), 0, stream>>>(KC, Qws, nbt, wstop, out);
    } else {
        selfatt_fused<<<dim3(T_ * B_), dim3(NTS), 0, stream>>>(
            pred, lc, SC, Wq, Wk, nbt, out);
    }
}